// Round 6
// baseline (92.026 us; speedup 1.0000x reference)
//
#include <hip/hip_runtime.h>

// SharedMultiCategoricalEncoder on MI355X — round 6: 4 pairs/thread,
// double-buffered gather pipeline under a fixed ~115-VGPR budget.
//
// Evidence: traffic scaling (bf16 table, nt hints) = no effect; 2x ILP
// (round 5) = -5.7 us. => latency/MLP-bound. VGPR cliff at 128 (4->2
// waves/SIMD) means "more outstanding dests" backfires; instead keep 16
// gather dests live (2-pair double buffer), prefetch all ids up front,
// store each pair immediately after consumption, refill the freed buffer
// right away so the VMEM queue never drains.

#define NPAIRS (8192 * 32)          // B*C = 262144
#define LL 8
#define NROWS 9311
#define D 64
#define TAB_ELEMS (NROWS * D)       // 595,904
#define QUARTER (NPAIRS / 4)        // 65536

typedef float  vfloat4 __attribute__((ext_vector_type(4)));
typedef int    vint4   __attribute__((ext_vector_type(4)));
typedef unsigned int  uint32;
typedef unsigned int  vuint4 __attribute__((ext_vector_type(4)));
typedef unsigned short vushort4 __attribute__((ext_vector_type(4)));

// ---- prologue: fp32 table -> bf16 (round-to-nearest-even) ------------------
__global__ __launch_bounds__(256) void
cvt_table_bf16(const vfloat4* __restrict__ src, vushort4* __restrict__ dst, int n4) {
    const int i = blockIdx.x * blockDim.x + threadIdx.x;
    if (i >= n4) return;
    const vfloat4 f = src[i];
    vushort4 o;
    #pragma unroll
    for (int k = 0; k < 4; ++k) {
        uint32 b = __float_as_uint(f[k]);
        b = (b + 0x7fff + ((b >> 16) & 1)) >> 16;   // RNE (inputs finite)
        o[k] = (unsigned short)b;
    }
    dst[i] = o;
}

// ---- main: 8 lanes/pair, 4 pairs/thread, 2-pair gather double-buffer -------
__global__ __launch_bounds__(256) void
SharedMultiCategoricalEncoder_kernel(const int* __restrict__ x,
                                     const vuint4* __restrict__ tab,   // bf16 table
                                     vfloat4* __restrict__ out4) {
    const int tid  = blockIdx.x * blockDim.x + threadIdx.x;
    const int base = tid >> 3;             // [0, QUARTER)
    const int sub  = tid & 7;              // channel chunk [sub*8, sub*8+8)
    const vint4* xp = (const vint4*)x;

    // All 4 pairs' ids issued up front (8 independent dwordx4 loads).
    vint4 ia[4], ib[4];
#pragma unroll
    for (int k = 0; k < 4; ++k) {
        const int p = base + k * QUARTER;
        ia[k] = xp[2 * p];
        ib[k] = xp[2 * p + 1];
    }

    // Double-buffered gather regs: only 16 dwordx4 dests live (64 VGPRs).
    vuint4 e[2][8];
#pragma unroll
    for (int k = 0; k < 2; ++k) {
        const int ids[LL] = { ia[k].x, ia[k].y, ia[k].z, ia[k].w,
                              ib[k].x, ib[k].y, ib[k].z, ib[k].w };
        #pragma unroll
        for (int l = 0; l < LL; ++l) e[k][l] = tab[ids[l] * 8 + sub];
    }

#pragma unroll
    for (int k = 0; k < 4; ++k) {
        const int ids[LL] = { ia[k].x, ia[k].y, ia[k].z, ia[k].w,
                              ib[k].x, ib[k].y, ib[k].z, ib[k].w };
        int cnt = 0;
        #pragma unroll
        for (int l = 0; l < LL; ++l) cnt += (ids[l] > 0);

        float acc[8] = {0.f};
        #pragma unroll
        for (int l = 0; l < LL; ++l) {
            #pragma unroll
            for (int q = 0; q < 4; ++q) {
                const uint32 u = e[k & 1][l][q];
                acc[2*q]   += __uint_as_float(u << 16);
                acc[2*q+1] += __uint_as_float(u & 0xffff0000u);
            }
        }

        // Refill the freed buffer with pair k+2's gathers before the divide/
        // store, so the VMEM queue stays fed.
        if (k + 2 < 4) {
            const int jds[LL] = { ia[k+2].x, ia[k+2].y, ia[k+2].z, ia[k+2].w,
                                  ib[k+2].x, ib[k+2].y, ib[k+2].z, ib[k+2].w };
            #pragma unroll
            for (int l = 0; l < LL; ++l) e[k & 1][l] = tab[jds[l] * 8 + sub];
        }

        const float s = 1.0f / (float)(cnt > 0 ? cnt : 1);
        const int p = base + k * QUARTER;
        vfloat4* op = out4 + p * 16 + sub * 2;
        op[0] = (vfloat4){acc[0], acc[1], acc[2], acc[3]} * s;
        op[1] = (vfloat4){acc[4], acc[5], acc[6], acc[7]} * s;
    }
}

extern "C" void kernel_launch(void* const* d_in, const int* in_sizes, int n_in,
                              void* d_out, int out_size, void* d_ws, size_t ws_size,
                              hipStream_t stream) {
    const int*   x   = (const int*)d_in[0];
    const float* emb = (const float*)d_in[1];
    float*       out = (float*)d_out;

    // bf16 table in workspace: 9311*64*2 B = 1.19 MB.
    const int n4 = TAB_ELEMS / 4;
    cvt_table_bf16<<<(n4 + 255) / 256, 256, 0, stream>>>(
        (const vfloat4*)emb, (vushort4*)d_ws, n4);

    const int threads = 256;
    const int blocks  = (QUARTER * 8) / threads;   // 2048 blocks, 524288 threads
    SharedMultiCategoricalEncoder_kernel<<<blocks, threads, 0, stream>>>(
        x, (const vuint4*)d_ws, (vfloat4*)out);
}